// Round 4
// baseline (468.768 us; speedup 1.0000x reference)
//
#include <hip/hip_runtime.h>
#include <hip/hip_bf16.h>
#include <math.h>

#define BB 4
#define SS 1024
#define HH 768
#define NHEAD 12
#define NN 32
#define MM 4
#define WD 768
#define AD 256
#define NC 97
#define SPK 64
#define DD 12
#define KP 160   // padded bilinear K (144 -> 160)

typedef __attribute__((ext_vector_type(8))) short short8;
typedef __attribute__((ext_vector_type(4))) short sshort4;
typedef __attribute__((ext_vector_type(4))) float float4_t;

__device__ inline unsigned short f2bf(float x) {
  union { float f; unsigned int u; } v; v.f = x;
  unsigned int r = v.u + 0x7fffu + ((v.u >> 16) & 1u);
  return (unsigned short)(r >> 16);
}
__device__ inline float bf2f(unsigned short x) {
  union { unsigned int u; float f; } v; v.u = ((unsigned int)x) << 16;
  return v.f;
}

// async global->LDS, 16B per lane; LDS dest = wave-uniform base + lane*16
__device__ __forceinline__ void gl_lds16(unsigned short* l, const unsigned short* g) {
  __builtin_amdgcn_global_load_lds(
      (const __attribute__((address_space(1))) unsigned int*)g,
      (__attribute__((address_space(3))) unsigned int*)l, 16, 0, 0);
}

__device__ __forceinline__ void transpose_tile(const float* __restrict__ in,
                                               unsigned short* __restrict__ out,
                                               int R, int C, int Cp, int t, int tilesR) {
  __shared__ float tile[32][33];
  int r0 = (t % tilesR) * 32, c0 = (t / tilesR) * 32;
  int tx = threadIdx.x & 31, ty = threadIdx.x >> 5;  // 32x8
#pragma unroll
  for (int i = 0; i < 32; i += 8) {
    int r = r0 + ty + i, c = c0 + tx;
    tile[ty + i][tx] = (c < C) ? in[(size_t)r * C + c] : 0.f;
  }
  __syncthreads();
#pragma unroll
  for (int i = 0; i < 32; i += 8) {
    int c = c0 + ty + i, r = r0 + tx;
    if (c < Cp) out[(size_t)c * R + r] = f2bf(tile[tx][ty + i]);
  }
}

// ---------------- front: all independent prep work in one launch -----------
// branches: ga gather (bf16) | F = A_bl^T@W_attn (bf16) | tb = 64*b_bl@W_attn
//           | zero e | seq cvt | WcT | WsoT | clfT | AblB pad | rep
__global__ __launch_bounds__(256) void k_front(
    const float* __restrict__ seq, const float* __restrict__ att,
    const int* __restrict__ ep, const float* __restrict__ W_c,
    const float* __restrict__ W_s, const float* __restrict__ W_o,
    const float* __restrict__ clf_W, const float* __restrict__ A_bl,
    const float* __restrict__ W_attn, const float* __restrict__ b_bl,
    unsigned short* __restrict__ gaB, unsigned short* __restrict__ FB,
    float* __restrict__ tb, float* __restrict__ ebuf,
    unsigned short* __restrict__ seqB, unsigned short* __restrict__ WcT,
    unsigned short* __restrict__ WsoT, unsigned short* __restrict__ clfT,
    unsigned short* __restrict__ AblB, unsigned short* __restrict__ repB) {
  int bid = blockIdx.x;
  int tid = threadIdx.x;
  if (bid < 1536) {  // ga: sum of 4 mention attention rows, bf16 out
    int h = bid % NHEAD;
    int bn = bid / NHEAD;
    int b = bn / NN;
    const int* e = ep + (size_t)bn * MM;
    int i0 = e[0], i1 = e[1], i2 = e[2], i3 = e[3];
    const float* ab = att + ((size_t)b * NHEAD + h) * SS * SS;
    unsigned short* go = gaB + ((size_t)bn * NHEAD + h) * SS;
#pragma unroll
    for (int r = 0; r < 4; ++r) {
      int s = tid + r * 256;
      go[s] = f2bf(ab[(size_t)i0 * SS + s] + ab[(size_t)i1 * SS + s] +
                   ab[(size_t)i2 * SS + s] + ab[(size_t)i3 * SS + s]);
    }
    return;
  }
  bid -= 1536;
  if (bid < 256) {  // F[a][k] = sum_w A_bl[w][k] * W_attn[w][a], bf16 padded
    int a = bid;
    int k = tid;
    if (k < KP) {
      float acc = 0.f;
      if (k < DD * DD) {
        for (int w = 0; w < WD; ++w)
          acc += A_bl[(size_t)w * (DD * DD) + k] * W_attn[(size_t)w * AD + a];
      }
      FB[(size_t)a * KP + k] = f2bf(acc);
    }
    return;
  }
  bid -= 256;
  if (bid < 1) {  // tb[a] = 64 * sum_w b_bl[w] * W_attn[w][a]
    int a = tid;
    float acc = 0.f;
    for (int w = 0; w < WD; ++w) acc += b_bl[w] * W_attn[(size_t)w * AD + a];
    tb[a] = (float)SPK * acc;
    return;
  }
  bid -= 1;
  if (bid < 16) {  // zero e (atomically accumulated later)
    int idx = bid * 256 + tid;
    if (idx < BB * NN * NN) ebuf[idx] = 0.f;
    return;
  }
  bid -= 16;
  if (bid < 3072) {  // seq fp32 -> bf16
    int i = (bid * 256 + tid) * 4;
    float4 v = *(const float4*)&seq[i];
    seqB[i + 0] = f2bf(v.x); seqB[i + 1] = f2bf(v.y);
    seqB[i + 2] = f2bf(v.z); seqB[i + 3] = f2bf(v.w);
    return;
  }
  bid -= 3072;
  if (bid < 576) { transpose_tile(W_c, WcT, HH, WD, WD, bid, 24); return; }
  bid -= 576;
  if (bid < 576) { transpose_tile(W_s, WsoT, HH, WD, WD, bid, 24); return; }
  bid -= 576;
  if (bid < 576) { transpose_tile(W_o, WsoT + (size_t)WD * HH, HH, WD, WD, bid, 24); return; }
  bid -= 576;
  if (bid < 96)  { transpose_tile(clf_W, clfT, WD, NC, 128, bid, 24); return; }
  bid -= 96;
  if (bid < 480) {  // A_bl [768][144] -> [768][160] bf16 zero-padded
    int idx = bid * 256 + tid;
    int w = idx / KP, pq = idx % KP;
    AblB[idx] = (pq < DD * DD) ? f2bf(A_bl[(size_t)w * DD * DD + pq]) : 0;
    return;
  }
  bid -= 480;
  {  // rep: logsumexp over mentions, bf16 out (128 blocks)
    int bn = bid; int b = bn / NN;
    const int* e = ep + (size_t)bn * MM;
    int i0 = e[0], i1 = e[1], i2 = e[2], i3 = e[3];
    const float* sb = seq + (size_t)b * SS * HH;
    for (int h = tid; h < HH; h += 256) {
      float v0 = sb[(size_t)i0 * HH + h];
      float v1 = sb[(size_t)i1 * HH + h];
      float v2 = sb[(size_t)i2 * HH + h];
      float v3 = sb[(size_t)i3 * HH + h];
      float mx = fmaxf(fmaxf(v0, v1), fmaxf(v2, v3));
      float s = expf(v0 - mx) + expf(v1 - mx) + expf(v2 - mx) + expf(v3 - mx);
      repB[(size_t)bn * HH + h] = f2bf(mx + logf(s));
    }
  }
}

// ---------------- pa: pairwise product over heads + normalize (bf16 in/out)
__global__ __launch_bounds__(256) void k_pa(const unsigned short* __restrict__ gaB,
                                            unsigned short* __restrict__ pa) {
  int t = blockIdx.x;               // b*N*N + i*N + j
  int j = t % NN;
  int i = (t / NN) % NN;
  int b = t / (NN * NN);
  const unsigned short* gi = gaB + ((size_t)(b * NN + i)) * NHEAD * SS;
  const unsigned short* gj = gaB + ((size_t)(b * NN + j)) * NHEAD * SS;
  int s0 = threadIdx.x * 4;
  float acc[4] = {0.f, 0.f, 0.f, 0.f};
#pragma unroll
  for (int h = 0; h < NHEAD; ++h) {
    sshort4 a4 = *(const sshort4*)&gi[h * SS + s0];
    sshort4 b4 = *(const sshort4*)&gj[h * SS + s0];
#pragma unroll
    for (int r = 0; r < 4; ++r)
      acc[r] += bf2f((unsigned short)a4[r]) * bf2f((unsigned short)b4[r]);
  }
  float tot = acc[0] + acc[1] + acc[2] + acc[3];
  __shared__ float red[256];
  red[threadIdx.x] = tot;
  __syncthreads();
  for (int o = 128; o > 0; o >>= 1) {
    if (threadIdx.x < o) red[threadIdx.x] += red[threadIdx.x + o];
    __syncthreads();
  }
  float inv = 1.0f / red[0];
  unsigned short ov[4];
#pragma unroll
  for (int r = 0; r < 4; ++r) ov[r] = f2bf(acc[r] * inv);
  *(sshort4*)&pa[(size_t)t * SS + s0] = *(sshort4*)ov;
}

// ---------------- bf16 MFMA GEMM, NT layout, async LDS staging -------------
// C[m,n] = sum_k A[m,k]*B[n,k];  A:[M][K] bf16, B:[N][K] bf16 (row stride ldb)
// MODE: 0 = fp32 C[m*ldc+n]; 1 = bf16 C[m*ldc+n]; 2 = fp32 C[n*ldc+m];
//       3 = fp32 C[m*ldc+n] + rcW[row(m)] + rcW[col(m)] + clf_b (final fuse)
//       4 = no C store; e[m] += sum_n tanh(acc+bias[n])*va[n]  (va in rcWp)
template <int MODE>
__global__ __launch_bounds__(256)
void k_mm(const unsigned short* __restrict__ A, const unsigned short* __restrict__ B,
          void* __restrict__ Cv, int Nc, int K, int ldb, int ldc,
          long long sA, long long sB, long long sC,
          const float* __restrict__ bias, float biasScale,
          const float* __restrict__ rcWp, const float* __restrict__ clf_b) {
  A += (long long)blockIdx.z * sA;
  B += (long long)blockIdx.z * sB;
  __shared__ __align__(16) unsigned short As[128 * 32];
  __shared__ __align__(16) unsigned short Bs[128 * 32];
  const int tid = threadIdx.x;
  const int m0 = blockIdx.y * 128;
  const int n0 = blockIdx.x * 128;
  const int lane = tid & 63;
  const int w = tid >> 6;
  const int wr = (w >> 1) * 64, wc = (w & 1) * 64;
  const int q = lane >> 4, l16 = lane & 15;
  const int lr = lane >> 2, lq = lane & 3;  // staging: row-in-16, 16B chunk
  float4_t acc[4][4] = {};
  const unsigned short* Ag0 = A + (size_t)(m0 + w * 16 + lr) * K + lq * 8;
  const unsigned short* Ag1 = Ag0 + (size_t)64 * K;
  const unsigned short* Bg0 = B + (size_t)(n0 + w * 16 + lr) * ldb + lq * 8;
  const unsigned short* Bg1 = Bg0 + (size_t)64 * ldb;
  unsigned short* Al0 = &As[(w * 16) * 32];
  unsigned short* Al1 = &As[(64 + w * 16) * 32];
  unsigned short* Bl0 = &Bs[(w * 16) * 32];
  unsigned short* Bl1 = &Bs[(64 + w * 16) * 32];
  for (int k0 = 0; k0 < K; k0 += 32) {
    gl_lds16(Al0, Ag0 + k0);
    gl_lds16(Al1, Ag1 + k0);
    gl_lds16(Bl0, Bg0 + k0);
    gl_lds16(Bl1, Bg1 + k0);
    __syncthreads();
    short8 af[4], bfr[4];
#pragma unroll
    for (int i = 0; i < 4; ++i)
      af[i] = *(const short8*)&As[(wr + i * 16 + l16) * 32 + q * 8];
#pragma unroll
    for (int j = 0; j < 4; ++j)
      bfr[j] = *(const short8*)&Bs[(wc + j * 16 + l16) * 32 + q * 8];
#pragma unroll
    for (int i = 0; i < 4; ++i)
#pragma unroll
      for (int j = 0; j < 4; ++j)
        acc[i][j] = __builtin_amdgcn_mfma_f32_16x16x32_bf16(af[i], bfr[j], acc[i][j], 0, 0, 0);
    __syncthreads();
  }
  if (MODE == 4) {  // e[m] += sum over this block's n of tanh(t)*v_attn
    float* ep = (float*)Cv;
#pragma unroll
    for (int i = 0; i < 4; ++i) {
#pragma unroll
      for (int r = 0; r < 4; ++r) {
        float part = 0.f;
#pragma unroll
        for (int j = 0; j < 4; ++j) {
          int n = n0 + wc + j * 16 + l16;
          float v = acc[i][j][r] + bias[n];
          part += tanhf(v) * rcWp[n];
        }
#pragma unroll
        for (int d = 1; d < 16; d <<= 1) part += __shfl_xor(part, d, 16);
        if (l16 == 0) atomicAdd(&ep[m0 + wr + i * 16 + q * 4 + r], part);
      }
    }
    return;
  }
  float* Cf = (float*)Cv + (long long)blockIdx.z * sC;
  unsigned short* Cb = (unsigned short*)Cv + (long long)blockIdx.z * sC;
#pragma unroll
  for (int i = 0; i < 4; ++i) {
    int mbase = m0 + wr + i * 16 + q * 4;
#pragma unroll
    for (int j = 0; j < 4; ++j) {
      int n = n0 + wc + j * 16 + l16;
      if (n < Nc) {
        float badd = bias ? biasScale * bias[n] : 0.f;
#pragma unroll
        for (int r = 0; r < 4; ++r) {
          int m = mbase + r;
          float v = acc[i][j][r] + badd;
          if (MODE == 3) {
            int b = m >> 10, ii = (m >> 5) & 31, jj = m & 31;
            v += rcWp[(size_t)(b * NN + ii) * NC + n] +
                 rcWp[(size_t)(BB * NN + b * NN + jj) * NC + n] + clf_b[n];
          }
          if (MODE == 1)      Cb[(size_t)m * ldc + n] = f2bf(v);
          else if (MODE == 2) Cf[(size_t)n * ldc + m] = v;
          else                Cf[(size_t)m * ldc + n] = v;
        }
      }
    }
  }
}

// ---------------- Zs/Zo -> Gram matrix M (bf16, padded to 160) ------------
__global__ __launch_bounds__(256) void k_M(const unsigned short* __restrict__ ctx,
                                           const float* __restrict__ rso,
                                           unsigned short* __restrict__ Mm) {
  int t = blockIdx.x;  // b*N*N + i*N + j
  const float* rsi = rso + (size_t)(t >> 5) * 1536;
  __shared__ float zsT[64 * 13];  // [k][p], padded to 13 -> conflict-free Gram
  __shared__ float zoT[64 * 13];
  const unsigned short* cx = ctx + (size_t)t * WD;
  for (int wd = threadIdx.x; wd < WD; wd += blockDim.x) {
    float c = bf2f(cx[wd]);
    int k = wd & 63, p = wd >> 6;
    zsT[k * 13 + p] = tanhf(rsi[wd] + c);
    zoT[k * 13 + p] = tanhf(rsi[WD + wd] + c);
  }
  __syncthreads();
  int pq = threadIdx.x;
  if (pq < KP) {
    float s = 0.f;
    if (pq < DD * DD) {
      int p = pq / DD, qq = pq % DD;
#pragma unroll
      for (int k = 0; k < SPK; ++k) s += zsT[k * 13 + p] * zoT[k * 13 + qq];
    }
    Mm[(size_t)t * KP + pq] = f2bf(s);
  }
}

// ---------------- fused softmax + rowctx/colctx + @clf_W -------------------
// block t in [0,256): which = t>>7, bn = t&127 -> b, x
// rcW[which*128+bn][c] = sum_o (sum_k a[k] g[pair(k)][o]) clf_W[o][c]
__global__ __launch_bounds__(256) void k_rowcolW(const float* __restrict__ e,
                                                 const unsigned short* __restrict__ g,
                                                 const float* __restrict__ clf_W,
                                                 float* __restrict__ rcW) {
  int t = blockIdx.x;
  int which = t >> 7;
  int bn = t & 127;
  int b = bn >> 5, x = bn & 31;
  int tid = threadIdx.x;
  __shared__ float av[NN];
  __shared__ float rcs[WD];
  if (tid < NN)
    av[tid] = (which == 0) ? e[(size_t)b * 1024 + x * NN + tid]
                           : e[(size_t)b * 1024 + tid * NN + x];
  __syncthreads();
  float mx = -1e30f;
#pragma unroll 8
  for (int k = 0; k < NN; ++k) mx = fmaxf(mx, av[k]);
  float sm = 0.f;
  float wk[NN];
#pragma unroll 8
  for (int k = 0; k < NN; ++k) { wk[k] = expf(av[k] - mx); sm += wk[k]; }
  float inv = 1.0f / sm;
  const unsigned short* gb = g + (size_t)b * 1024 * WD;
  for (int o = tid; o < WD; o += 256) {
    float s = 0.f;
#pragma unroll 8
    for (int k = 0; k < NN; ++k) {
      int pair = (which == 0) ? x * NN + k : k * NN + x;
      s += wk[k] * bf2f(gb[(size_t)pair * WD + o]);
    }
    rcs[o] = s * inv;
  }
  __syncthreads();
  if (tid < NC) {
    float s = 0.f;
    for (int o = 0; o < WD; ++o) s += rcs[o] * clf_W[(size_t)o * NC + tid];
    rcW[(size_t)(which * 128 + bn) * NC + tid] = s;
  }
}

extern "C" void kernel_launch(void* const* d_in, const int* in_sizes, int n_in,
                              void* d_out, int out_size, void* d_ws, size_t ws_size,
                              hipStream_t stream) {
  const float* seq    = (const float*)d_in[0];
  const float* att    = (const float*)d_in[1];
  const int*   ep     = (const int*)d_in[2];
  const float* W_s    = (const float*)d_in[3];
  const float* W_o    = (const float*)d_in[4];
  const float* W_c    = (const float*)d_in[5];
  const float* A_bl   = (const float*)d_in[6];
  const float* b_bl   = (const float*)d_in[7];
  const float* W_attn = (const float*)d_in[8];
  const float* v_attn = (const float*)d_in[9];
  const float* clf_W  = (const float*)d_in[10];
  const float* clf_b  = (const float*)d_in[11];
  float* out = (float*)d_out;

  char* base = (char*)d_ws;
  size_t off = 0;
  auto alloc = [&](size_t bytes) {
    char* p = base + off;
    off += (bytes + 255) & ~(size_t)255;
    return p;
  };
  unsigned short* repB = (unsigned short*)alloc((size_t)BB * NN * HH * 2);
  float* rso  = (float*)alloc((size_t)BB * NN * 2 * WD * 4);              // [128][1536]
  unsigned short* gaB  = (unsigned short*)alloc((size_t)BB * NN * NHEAD * SS * 2);
  unsigned short* paB  = (unsigned short*)alloc((size_t)BB * NN * NN * SS * 2);  // reused: g bf16
  unsigned short* seqB = (unsigned short*)alloc((size_t)BB * SS * HH * 2);
  unsigned short* WcT  = (unsigned short*)alloc((size_t)HH * WD * 2);
  unsigned short* clfT = (unsigned short*)alloc((size_t)128 * WD * 2);
  unsigned short* WsoT = (unsigned short*)alloc((size_t)2 * WD * HH * 2); // [1536][768]
  unsigned short* scT  = (unsigned short*)alloc((size_t)WD * BB * SS * 2);
  unsigned short* ctxB = (unsigned short*)alloc((size_t)BB * NN * NN * WD * 2);
  unsigned short* MmB  = (unsigned short*)alloc((size_t)BB * NN * NN * KP * 2);
  unsigned short* AblB = (unsigned short*)alloc((size_t)WD * KP * 2);
  unsigned short* FB   = (unsigned short*)alloc((size_t)AD * KP * 2);
  float* tb   = (float*)alloc((size_t)AD * 4);
  float* ebuf = (float*)alloc((size_t)BB * NN * NN * 4);
  float* rcW  = (float*)alloc((size_t)2 * BB * NN * NC * 4);
  unsigned short* gB = paB;               // alias: pa dead after ctx GEMM

  const float* nof = nullptr;

  // 1. front: ga, F, tb, zero-e, seq cvt, transposes, Abl pad, rep
  k_front<<<dim3(7313), dim3(256), 0, stream>>>(
      seq, att, ep, W_c, W_s, W_o, clf_W, A_bl, W_attn, b_bl,
      gaB, FB, tb, ebuf, seqB, WcT, WsoT, clfT, AblB, repB);

  // 2. scT[w][b*S+s] = (seq@W_c)^T
  k_mm<1><<<dim3(BB * SS / 128, WD / 128, 1), dim3(256), 0, stream>>>(
      WcT, seqB, scT, BB * SS, HH, HH, BB * SS, 0LL, 0LL, 0LL, nof, 0.f, nof, nof);

  // 3. rso[bn][{W_s|W_o}] = rep @ [W_s|W_o] (C transposed store)
  k_mm<2><<<dim3(1, 12, 1), dim3(256), 0, stream>>>(
      WsoT, repB, rso, BB * NN, HH, HH, 2 * WD, 0LL, 0LL, 0LL, nof, 0.f, nof, nof);

  // 4. pa (normalized, bf16 in/out)
  k_pa<<<dim3(BB * NN * NN), dim3(256), 0, stream>>>(gaB, paB);

  // 5. ctx = pa @ sc (bf16 out)
  k_mm<1><<<dim3(WD / 128, NN * NN / 128, BB), dim3(256), 0, stream>>>(
      paB, scT, ctxB, WD, SS, BB * SS, WD,
      (long long)NN * NN * SS, (long long)SS, (long long)NN * NN * WD,
      nof, 0.f, nof, nof);

  // 6. M (Gram of Zs/Zo groups), bf16 padded [4096][160]
  k_M<<<dim3(BB * NN * NN), dim3(256), 0, stream>>>(ctxB, rso, MmB);

  // 7. e[m] = sum_a tanh((M@F^T)[m,a] + tb[a]) * v_attn[a]  (t never stored)
  k_mm<4><<<dim3(AD / 128, BB * NN * NN / 128, 1), dim3(256), 0, stream>>>(
      MmB, FB, ebuf, AD, KP, KP, 0, 0LL, 0LL, 0LL, tb, 1.f, v_attn, nof);

  // 8. g = M @ A_bl^T + 64*b_bl (bf16 out)
  k_mm<1><<<dim3(WD / 128, BB * NN * NN / 128, 1), dim3(256), 0, stream>>>(
      MmB, AblB, gB, WD, KP, KP, WD, 0LL, 0LL, 0LL, b_bl, (float)SPK, nof, nof);

  // 9. fused softmax + rowctx/colctx + @clf_W
  k_rowcolW<<<dim3(2 * BB * NN), dim3(256), 0, stream>>>(ebuf, gB, clf_W, rcW);

  // 10. out = g @ clf_W + rcW_row[i] + rcW_col[j] + clf_b (fused final)
  k_mm<3><<<dim3(1, BB * NN * NN / 128, 1), dim3(256), 0, stream>>>(
      gB, clfT, out, NC, WD, WD, NC, 0LL, 0LL, 0LL, nof, 0.f, rcW, clf_b);
}

// Round 5
// 408.056 us; speedup vs baseline: 1.1488x; 1.1488x over previous
//
#include <hip/hip_runtime.h>
#include <hip/hip_bf16.h>
#include <math.h>

#define BB 4
#define SS 1024
#define HH 768
#define NHEAD 12
#define NN 32
#define MM 4
#define WD 768
#define AD 256
#define NC 97
#define SPK 64
#define DD 12
#define KP 160   // padded bilinear K (144 -> 160)

typedef __attribute__((ext_vector_type(8))) short short8;
typedef __attribute__((ext_vector_type(4))) short sshort4;
typedef __attribute__((ext_vector_type(4))) float float4_t;

__device__ inline unsigned short f2bf(float x) {
  union { float f; unsigned int u; } v; v.f = x;
  unsigned int r = v.u + 0x7fffu + ((v.u >> 16) & 1u);
  return (unsigned short)(r >> 16);
}
__device__ inline float bf2f(unsigned short x) {
  union { unsigned int u; float f; } v; v.u = ((unsigned int)x) << 16;
  return v.f;
}

// async global->LDS, 16B per lane; LDS dest = wave-uniform base + lane*16
__device__ __forceinline__ void gl_lds16(unsigned short* l, const unsigned short* g) {
  __builtin_amdgcn_global_load_lds(
      (const __attribute__((address_space(1))) unsigned int*)g,
      (__attribute__((address_space(3))) unsigned int*)l, 16, 0, 0);
}

__device__ __forceinline__ void transpose_tile(const float* __restrict__ in,
                                               unsigned short* __restrict__ out,
                                               int R, int C, int Cp, int t, int tilesR) {
  __shared__ float tile[32][33];
  int r0 = (t % tilesR) * 32, c0 = (t / tilesR) * 32;
  int tx = threadIdx.x & 31, ty = threadIdx.x >> 5;  // 32x8
#pragma unroll
  for (int i = 0; i < 32; i += 8) {
    int r = r0 + ty + i, c = c0 + tx;
    tile[ty + i][tx] = (c < C) ? in[(size_t)r * C + c] : 0.f;
  }
  __syncthreads();
#pragma unroll
  for (int i = 0; i < 32; i += 8) {
    int c = c0 + ty + i, r = r0 + tx;
    if (c < Cp) out[(size_t)c * R + r] = f2bf(tile[tx][ty + i]);
  }
}

// ---------------- 64x64 MFMA GEMM core: 4 waves as 2x2 of 32x32 ------------
// acc[i][j] covers m = m0 + wr2 + i*16 + q*4 + r,  n = n0 + wc2 + j*16 + l16
__device__ __forceinline__ void gemm64(
    const unsigned short* __restrict__ A, int lda,
    const unsigned short* __restrict__ B, int ldb, int K,
    int m0, int n0, unsigned short* As, unsigned short* Bs,
    float4_t acc[2][2]) {
  const int tid = threadIdx.x;
  const int lane = tid & 63;
  const int w = tid >> 6;
  const int lr = lane >> 2, lq = lane & 3;
  const unsigned short* Ag = A + (size_t)(m0 + w * 16 + lr) * lda + lq * 8;
  const unsigned short* Bg = B + (size_t)(n0 + w * 16 + lr) * ldb + lq * 8;
  unsigned short* Al = &As[(w * 16) * 32];
  unsigned short* Bl = &Bs[(w * 16) * 32];
  const int wr2 = (w >> 1) * 32, wc2 = (w & 1) * 32;
  const int q = lane >> 4, l16 = lane & 15;
  for (int k0 = 0; k0 < K; k0 += 32) {
    gl_lds16(Al, Ag + k0);
    gl_lds16(Bl, Bg + k0);
    __syncthreads();
    short8 af[2], bfr[2];
#pragma unroll
    for (int i = 0; i < 2; ++i)
      af[i] = *(const short8*)&As[(wr2 + i * 16 + l16) * 32 + q * 8];
#pragma unroll
    for (int j = 0; j < 2; ++j)
      bfr[j] = *(const short8*)&Bs[(wc2 + j * 16 + l16) * 32 + q * 8];
#pragma unroll
    for (int i = 0; i < 2; ++i)
#pragma unroll
      for (int j = 0; j < 2; ++j)
        acc[i][j] = __builtin_amdgcn_mfma_f32_16x16x32_bf16(af[i], bfr[j], acc[i][j], 0, 0, 0);
    __syncthreads();
  }
}

// ---------------- front: all independent prep work in one launch -----------
__global__ __launch_bounds__(256) void k_front(
    const float* __restrict__ seq, const float* __restrict__ att,
    const int* __restrict__ ep, const float* __restrict__ W_c,
    const float* __restrict__ W_s, const float* __restrict__ W_o,
    const float* __restrict__ clf_W, const float* __restrict__ clf_b,
    const float* __restrict__ A_bl, const float* __restrict__ W_attn,
    const float* __restrict__ b_bl,
    unsigned short* __restrict__ gaB, unsigned short* __restrict__ BcatB,
    float* __restrict__ tb, float* __restrict__ tb2, float* __restrict__ ebuf,
    unsigned short* __restrict__ seqB, unsigned short* __restrict__ WcT,
    unsigned short* __restrict__ WsoT, unsigned short* __restrict__ repB) {
  int bid = blockIdx.x;
  int tid = threadIdx.x;
  if (bid < 1536) {  // ga: sum of 4 mention attention rows, bf16 out
    int h = bid % NHEAD;
    int bn = bid / NHEAD;
    int b = bn / NN;
    const int* e = ep + (size_t)bn * MM;
    int i0 = e[0], i1 = e[1], i2 = e[2], i3 = e[3];
    const float* ab = att + ((size_t)b * NHEAD + h) * SS * SS;
    unsigned short* go = gaB + ((size_t)bn * NHEAD + h) * SS;
#pragma unroll
    for (int r = 0; r < 4; ++r) {
      int s = tid + r * 256;
      go[s] = f2bf(ab[(size_t)i0 * SS + s] + ab[(size_t)i1 * SS + s] +
                   ab[(size_t)i2 * SS + s] + ab[(size_t)i3 * SS + s]);
    }
    return;
  }
  bid -= 1536;
  if (bid < 256) {  // F[a][k] = sum_w A_bl[w][k]*W_attn[w][a] -> Bcat rows 768..1023
    int a = bid, k = tid;
    if (k < KP) {
      float acc = 0.f;
      if (k < DD * DD) {
        for (int w = 0; w < WD; ++w)
          acc += A_bl[(size_t)w * (DD * DD) + k] * W_attn[(size_t)w * AD + a];
      }
      BcatB[(size_t)(768 + a) * KP + k] = f2bf(acc);
    }
    return;
  }
  bid -= 256;
  if (bid < 128) {  // H[c][k] = sum_o clf_W[o][c]*A_bl[o][k] -> Bcat rows 1024..1151
    int c = bid, k = tid;
    if (k < KP) {
      float acc = 0.f;
      if (k < DD * DD && c < NC) {
        for (int o = 0; o < WD; ++o)
          acc += clf_W[(size_t)o * NC + c] * A_bl[(size_t)o * (DD * DD) + k];
      }
      BcatB[(size_t)(1024 + c) * KP + k] = f2bf(acc);
    }
    return;
  }
  bid -= 128;
  if (bid < 1) {  // tb[a] = 64 * sum_w b_bl[w]*W_attn[w][a]
    int a = tid;
    float acc = 0.f;
    for (int w = 0; w < WD; ++w) acc += b_bl[w] * W_attn[(size_t)w * AD + a];
    tb[a] = (float)SPK * acc;
    return;
  }
  bid -= 1;
  if (bid < 1) {  // tb2[c] = 64 * b_bl@clf_W + clf_b
    int c = tid;
    if (c < 128) {
      float acc = 0.f;
      if (c < NC) {
        for (int o = 0; o < WD; ++o) acc += b_bl[o] * clf_W[(size_t)o * NC + c];
        acc = (float)SPK * acc + clf_b[c];
      }
      tb2[c] = acc;
    }
    return;
  }
  bid -= 1;
  if (bid < 16) {  // zero e
    int idx = bid * 256 + tid;
    if (idx < BB * NN * NN) ebuf[idx] = 0.f;
    return;
  }
  bid -= 16;
  if (bid < 3072) {  // seq fp32 -> bf16
    int i = (bid * 256 + tid) * 4;
    float4 v = *(const float4*)&seq[i];
    seqB[i + 0] = f2bf(v.x); seqB[i + 1] = f2bf(v.y);
    seqB[i + 2] = f2bf(v.z); seqB[i + 3] = f2bf(v.w);
    return;
  }
  bid -= 3072;
  if (bid < 576) { transpose_tile(W_c, WcT, HH, WD, WD, bid, 24); return; }
  bid -= 576;
  if (bid < 576) { transpose_tile(W_s, WsoT, HH, WD, WD, bid, 24); return; }
  bid -= 576;
  if (bid < 576) { transpose_tile(W_o, WsoT + (size_t)WD * HH, HH, WD, WD, bid, 24); return; }
  bid -= 576;
  if (bid < 480) {  // A_bl [768][144] -> Bcat rows 0..767 (zero-padded to 160)
    int idx = bid * 256 + tid;
    int w = idx / KP, pq = idx % KP;
    BcatB[idx] = (pq < DD * DD) ? f2bf(A_bl[(size_t)w * DD * DD + pq]) : 0;
    return;
  }
  bid -= 480;
  {  // rep: logsumexp over mentions, bf16 out (128 blocks)
    int bn = bid; int b = bn / NN;
    const int* e = ep + (size_t)bn * MM;
    int i0 = e[0], i1 = e[1], i2 = e[2], i3 = e[3];
    const float* sb = seq + (size_t)b * SS * HH;
    for (int h = tid; h < HH; h += 256) {
      float v0 = sb[(size_t)i0 * HH + h];
      float v1 = sb[(size_t)i1 * HH + h];
      float v2 = sb[(size_t)i2 * HH + h];
      float v3 = sb[(size_t)i3 * HH + h];
      float mx = fmaxf(fmaxf(v0, v1), fmaxf(v2, v3));
      float s = expf(v0 - mx) + expf(v1 - mx) + expf(v2 - mx) + expf(v3 - mx);
      repB[(size_t)bn * HH + h] = f2bf(mx + logf(s));
    }
  }
}

// ---------------- mid: pa (1024) + scT GEMM (768) + rso GEMM (48) ----------
__global__ __launch_bounds__(256) void k_mid(
    const unsigned short* __restrict__ gaB, unsigned short* __restrict__ paB,
    const unsigned short* __restrict__ WcT, const unsigned short* __restrict__ seqB,
    unsigned short* __restrict__ scT,
    const unsigned short* __restrict__ WsoT, const unsigned short* __restrict__ repB,
    float* __restrict__ rso) {
  __shared__ __align__(16) unsigned short As[64 * 32];
  __shared__ __align__(16) unsigned short Bs[64 * 32];
  int bid = blockIdx.x;
  int tid = threadIdx.x;
  if (bid < 1024) {  // pa: pairwise product over heads + normalize
    int t = bid;
    int j = t % NN;
    int i = (t / NN) % NN;
    int b = t / (NN * NN);
    const unsigned short* gi = gaB + ((size_t)(b * NN + i)) * NHEAD * SS;
    const unsigned short* gj = gaB + ((size_t)(b * NN + j)) * NHEAD * SS;
    int s0 = tid * 4;
    float acc[4] = {0.f, 0.f, 0.f, 0.f};
#pragma unroll
    for (int h = 0; h < NHEAD; ++h) {
      sshort4 a4 = *(const sshort4*)&gi[h * SS + s0];
      sshort4 b4 = *(const sshort4*)&gj[h * SS + s0];
#pragma unroll
      for (int r = 0; r < 4; ++r)
        acc[r] += bf2f((unsigned short)a4[r]) * bf2f((unsigned short)b4[r]);
    }
    float tot = acc[0] + acc[1] + acc[2] + acc[3];
    float* red = (float*)As;
    red[tid] = tot;
    __syncthreads();
    for (int o = 128; o > 0; o >>= 1) {
      if (tid < o) red[tid] += red[tid + o];
      __syncthreads();
    }
    float inv = 1.0f / red[0];
    unsigned short ov[4];
#pragma unroll
    for (int r = 0; r < 4; ++r) ov[r] = f2bf(acc[r] * inv);
    *(sshort4*)&paB[(size_t)t * SS + s0] = *(sshort4*)ov;
    return;
  }
  const int lane = tid & 63, w = tid >> 6;
  const int wr2 = (w >> 1) * 32, wc2 = (w & 1) * 32;
  const int q = lane >> 4, l16 = lane & 15;
  float4_t acc[2][2] = {};
  if (bid < 1024 + 768) {  // scT = (seq@W_c)^T : M=768(w), N=4096(s), K=768
    int b2 = bid - 1024;
    int m0 = (b2 >> 6) * 64, n0 = (b2 & 63) * 64;
    gemm64(WcT, HH, seqB, HH, HH, m0, n0, As, Bs, acc);
#pragma unroll
    for (int i = 0; i < 2; ++i)
#pragma unroll
      for (int j = 0; j < 2; ++j)
#pragma unroll
        for (int r = 0; r < 4; ++r) {
          int m = m0 + wr2 + i * 16 + q * 4 + r;
          int n = n0 + wc2 + j * 16 + l16;
          scT[(size_t)m * (BB * SS) + n] = f2bf(acc[i][j][r]);
        }
    return;
  }
  {  // rso = rep @ [W_s|W_o], transposed store: M=1536, N=128, K=768
    int b3 = bid - 1792;
    int m0 = (b3 >> 1) * 64, n0 = (b3 & 1) * 64;
    gemm64(WsoT, HH, repB, HH, HH, m0, n0, As, Bs, acc);
#pragma unroll
    for (int i = 0; i < 2; ++i)
#pragma unroll
      for (int j = 0; j < 2; ++j)
#pragma unroll
        for (int r = 0; r < 4; ++r) {
          int m = m0 + wr2 + i * 16 + q * 4 + r;
          int n = n0 + wc2 + j * 16 + l16;
          rso[(size_t)n * 1536 + m] = acc[i][j][r];
        }
  }
}

// ---------------- ctx = pa @ sc (bf16): per doc M=1024, N=768, K=1024 ------
__global__ __launch_bounds__(256) void k_ctx(
    const unsigned short* __restrict__ paB, const unsigned short* __restrict__ scT,
    unsigned short* __restrict__ ctxB) {
  __shared__ __align__(16) unsigned short As[64 * 32];
  __shared__ __align__(16) unsigned short Bs[64 * 32];
  int bid = blockIdx.x;
  int doc = bid / 192;
  int r2 = bid % 192;
  int n0 = (r2 % 12) * 64, m0 = (r2 / 12) * 64;
  const int tid = threadIdx.x;
  const int lane = tid & 63, w = tid >> 6;
  const int wr2 = (w >> 1) * 32, wc2 = (w & 1) * 32;
  const int q = lane >> 4, l16 = lane & 15;
  float4_t acc[2][2] = {};
  gemm64(paB + (size_t)doc * SS * SS, SS, scT + (size_t)doc * SS, BB * SS, SS,
         m0, n0, As, Bs, acc);
  unsigned short* cb = ctxB + (size_t)doc * SS * WD;
#pragma unroll
  for (int i = 0; i < 2; ++i)
#pragma unroll
    for (int j = 0; j < 2; ++j)
#pragma unroll
      for (int r = 0; r < 4; ++r) {
        int m = m0 + wr2 + i * 16 + q * 4 + r;
        int n = n0 + wc2 + j * 16 + l16;
        cb[(size_t)m * WD + n] = f2bf(acc[i][j][r]);
      }
}

// ---------------- Zs/Zo -> Gram matrix M (bf16, padded to 160) ------------
__global__ __launch_bounds__(256) void k_M(const unsigned short* __restrict__ ctx,
                                           const float* __restrict__ rso,
                                           unsigned short* __restrict__ Mm) {
  int t = blockIdx.x;  // b*N*N + i*N + j
  const float* rsi = rso + (size_t)(t >> 5) * 1536;
  __shared__ float zsT[64 * 13];  // [k][p], padded to 13 -> conflict-free Gram
  __shared__ float zoT[64 * 13];
  const unsigned short* cx = ctx + (size_t)t * WD;
  for (int wd = threadIdx.x; wd < WD; wd += blockDim.x) {
    float c = bf2f(cx[wd]);
    int k = wd & 63, p = wd >> 6;
    zsT[k * 13 + p] = tanhf(rsi[wd] + c);
    zoT[k * 13 + p] = tanhf(rsi[WD + wd] + c);
  }
  __syncthreads();
  int pq = threadIdx.x;
  if (pq < KP) {
    float s = 0.f;
    if (pq < DD * DD) {
      int p = pq / DD, qq = pq % DD;
#pragma unroll
      for (int k = 0; k < SPK; ++k) s += zsT[k * 13 + p] * zoT[k * 13 + qq];
    }
    Mm[(size_t)t * KP + pq] = f2bf(s);
  }
}

// ---------------- eg: M@Bcat^T -> {g bf16 | e-reduce | out-main} -----------
// M=4096, N=1152 (768 g | 256 e | 128 out), K=160
__global__ __launch_bounds__(256) void k_eg(
    const unsigned short* __restrict__ MmB, const unsigned short* __restrict__ BcatB,
    unsigned short* __restrict__ gB, float* __restrict__ ebuf,
    float* __restrict__ out, const float* __restrict__ b_bl,
    const float* __restrict__ tb, const float* __restrict__ tb2,
    const float* __restrict__ v_attn) {
  __shared__ __align__(16) unsigned short As[64 * 32];
  __shared__ __align__(16) unsigned short Bs[64 * 32];
  int bid = blockIdx.x;
  int n0 = (bid % 18) * 64, m0 = (bid / 18) * 64;
  const int tid = threadIdx.x;
  const int lane = tid & 63, w = tid >> 6;
  const int wr2 = (w >> 1) * 32, wc2 = (w & 1) * 32;
  const int q = lane >> 4, l16 = lane & 15;
  float4_t acc[2][2] = {};
  gemm64(MmB, KP, BcatB, KP, KP, m0, n0, As, Bs, acc);
  if (n0 < 768) {  // g = M@Abl^T + 64*b_bl (bf16)
#pragma unroll
    for (int i = 0; i < 2; ++i)
#pragma unroll
      for (int j = 0; j < 2; ++j) {
        int n = n0 + wc2 + j * 16 + l16;
        float badd = (float)SPK * b_bl[n];
#pragma unroll
        for (int r = 0; r < 4; ++r) {
          int m = m0 + wr2 + i * 16 + q * 4 + r;
          gB[(size_t)m * WD + n] = f2bf(acc[i][j][r] + badd);
        }
      }
  } else if (n0 < 1024) {  // e[m] += sum_a tanh(t[m,a])*v_attn[a]
#pragma unroll
    for (int i = 0; i < 2; ++i) {
#pragma unroll
      for (int r = 0; r < 4; ++r) {
        float part = 0.f;
#pragma unroll
        for (int j = 0; j < 2; ++j) {
          int a = n0 - 768 + wc2 + j * 16 + l16;
          part += tanhf(acc[i][j][r] + tb[a]) * v_attn[a];
        }
#pragma unroll
        for (int d = 1; d < 16; d <<= 1) part += __shfl_xor(part, d, 16);
        if (l16 == 0)
          atomicAdd(&ebuf[m0 + wr2 + i * 16 + q * 4 + r], part);
      }
    }
  } else {  // out-main = M@H^T + tb2 (fp32, rowcol terms added later)
#pragma unroll
    for (int i = 0; i < 2; ++i)
#pragma unroll
      for (int j = 0; j < 2; ++j) {
        int c = n0 - 1024 + wc2 + j * 16 + l16;
        if (c < NC) {
          float badd = tb2[c];
#pragma unroll
          for (int r = 0; r < 4; ++r) {
            int m = m0 + wr2 + i * 16 + q * 4 + r;
            out[(size_t)m * NC + c] = acc[i][j][r] + badd;
          }
        }
      }
  }
}

// ---------------- fused softmax + rowctx/colctx + @clf_W -> atomic out -----
__global__ __launch_bounds__(256) void k_rowcolW(const float* __restrict__ e,
                                                 const unsigned short* __restrict__ g,
                                                 const float* __restrict__ clf_W,
                                                 float* __restrict__ out) {
  int t = blockIdx.x;
  int which = t >> 7;
  int bn = t & 127;
  int b = bn >> 5, x = bn & 31;
  int tid = threadIdx.x;
  __shared__ float av[NN];
  __shared__ float rcs[WD];
  if (tid < NN)
    av[tid] = (which == 0) ? e[(size_t)b * 1024 + x * NN + tid]
                           : e[(size_t)b * 1024 + tid * NN + x];
  __syncthreads();
  float mx = -1e30f;
#pragma unroll 8
  for (int k = 0; k < NN; ++k) mx = fmaxf(mx, av[k]);
  float sm = 0.f;
  float wk[NN];
#pragma unroll 8
  for (int k = 0; k < NN; ++k) { wk[k] = expf(av[k] - mx); sm += wk[k]; }
  float inv = 1.0f / sm;
  const unsigned short* gb = g + (size_t)b * 1024 * WD;
  for (int o = tid; o < WD; o += 256) {
    float s = 0.f;
#pragma unroll 8
    for (int k = 0; k < NN; ++k) {
      int pair = (which == 0) ? x * NN + k : k * NN + x;
      s += wk[k] * bf2f(gb[(size_t)pair * WD + o]);
    }
    rcs[o] = s * inv;
  }
  __syncthreads();
  if (tid < NC) {
    float s = 0.f;
    for (int o = 0; o < WD; ++o) s += rcs[o] * clf_W[(size_t)o * NC + tid];
    if (which == 0) {
      float* ob = out + ((size_t)(b * NN + x) * NN) * NC + tid;
#pragma unroll 4
      for (int jj = 0; jj < NN; ++jj) atomicAdd(&ob[(size_t)jj * NC], s);
    } else {
      float* ob = out + ((size_t)(b * NN) * NN + x) * NC + tid;
#pragma unroll 4
      for (int ii = 0; ii < NN; ++ii) atomicAdd(&ob[(size_t)ii * NN * NC], s);
    }
  }
}

extern "C" void kernel_launch(void* const* d_in, const int* in_sizes, int n_in,
                              void* d_out, int out_size, void* d_ws, size_t ws_size,
                              hipStream_t stream) {
  const float* seq    = (const float*)d_in[0];
  const float* att    = (const float*)d_in[1];
  const int*   ep     = (const int*)d_in[2];
  const float* W_s    = (const float*)d_in[3];
  const float* W_o    = (const float*)d_in[4];
  const float* W_c    = (const float*)d_in[5];
  const float* A_bl   = (const float*)d_in[6];
  const float* b_bl   = (const float*)d_in[7];
  const float* W_attn = (const float*)d_in[8];
  const float* v_attn = (const float*)d_in[9];
  const float* clf_W  = (const float*)d_in[10];
  const float* clf_b  = (const float*)d_in[11];
  float* out = (float*)d_out;

  char* base = (char*)d_ws;
  size_t off = 0;
  auto alloc = [&](size_t bytes) {
    char* p = base + off;
    off += (bytes + 255) & ~(size_t)255;
    return p;
  };
  unsigned short* repB = (unsigned short*)alloc((size_t)BB * NN * HH * 2);
  float* rso  = (float*)alloc((size_t)BB * NN * 2 * WD * 4);              // [128][1536]
  unsigned short* gaB  = (unsigned short*)alloc((size_t)BB * NN * NHEAD * SS * 2);
  unsigned short* paB  = (unsigned short*)alloc((size_t)BB * NN * NN * SS * 2);  // reused: g
  unsigned short* seqB = (unsigned short*)alloc((size_t)BB * SS * HH * 2);
  unsigned short* WcT  = (unsigned short*)alloc((size_t)HH * WD * 2);
  unsigned short* WsoT = (unsigned short*)alloc((size_t)2 * WD * HH * 2); // [1536][768]
  unsigned short* scT  = (unsigned short*)alloc((size_t)WD * BB * SS * 2);
  unsigned short* ctxB = (unsigned short*)alloc((size_t)BB * NN * NN * WD * 2);
  unsigned short* MmB  = (unsigned short*)alloc((size_t)BB * NN * NN * KP * 2);
  unsigned short* BcatB= (unsigned short*)alloc((size_t)1152 * KP * 2);   // Abl|F|H
  float* tb   = (float*)alloc((size_t)AD * 4);
  float* tb2  = (float*)alloc((size_t)128 * 4);
  float* ebuf = (float*)alloc((size_t)BB * NN * NN * 4);
  unsigned short* gB = paB;               // alias: pa dead after ctx GEMM

  // 1. front: ga, F, H, tb, tb2, zero-e, seq cvt, transposes, Abl pad, rep
  k_front<<<dim3(7346), dim3(256), 0, stream>>>(
      seq, att, ep, W_c, W_s, W_o, clf_W, clf_b, A_bl, W_attn, b_bl,
      gaB, BcatB, tb, tb2, ebuf, seqB, WcT, WsoT, repB);

  // 2. mid: pa (1024) + scT GEMM (768) + rso GEMM (48)
  k_mid<<<dim3(1840), dim3(256), 0, stream>>>(
      gaB, paB, WcT, seqB, scT, WsoT, repB, rso);

  // 3. ctx = pa @ sc (bf16 out), 768 blocks
  k_ctx<<<dim3(768), dim3(256), 0, stream>>>(paB, scT, ctxB);

  // 4. M (Gram of Zs/Zo groups), bf16 padded [4096][160]
  k_M<<<dim3(BB * NN * NN), dim3(256), 0, stream>>>(ctxB, rso, MmB);

  // 5. eg: g + e + out-main in one GEMM dispatch (1152 blocks)
  k_eg<<<dim3(1152), dim3(256), 0, stream>>>(
      MmB, BcatB, gB, ebuf, out, b_bl, tb, tb2, v_attn);

  // 6. fused softmax + rowctx/colctx + @clf_W, atomically added into out
  k_rowcolW<<<dim3(2 * BB * NN), dim3(256), 0, stream>>>(ebuf, gB, clf_W, out);
}